// Round 7
// baseline (427.566 us; speedup 1.0000x reference)
//
#include <hip/hip_runtime.h>
#include <cmath>

// ---------------------------------------------------------------------------
// PointCloudFeatureExtractor — full pipeline port (fp32).
// Round 7: knn occupancy pin (launch_bounds 256,8) + 4-way min ILP;
//          flat-grid pool_max (no idle lanes).
// ---------------------------------------------------------------------------

__device__ __forceinline__ unsigned flipf(float f) {
    unsigned u = __float_as_uint(f);
    return (u & 0x80000000u) ? ~u : (u | 0x80000000u);
}
__device__ __forceinline__ float unflip(unsigned u) {
    unsigned r = (u & 0x80000000u) ? (u & 0x7fffffffu) : ~u;
    return __uint_as_float(r);
}

// vq[i] = {x, y, z, (x*x+y*y)+z*z}  (exact op order of the distance formula)
__global__ __launch_bounds__(256) void precompute_vq(
    const float* __restrict__ v, float4* __restrict__ vq, int n)
{
#pragma clang fp contract(off)
    const int i = blockIdx.x * 256 + threadIdx.x;
    if (i < n) {
        const float x = v[i * 3 + 0];
        const float y = v[i * 3 + 1];
        const float z = v[i * 3 + 2];
        float4 o; o.x = x; o.y = y; o.z = z; o.w = (x * x + y * y) + z * z;
        vq[i] = o;
    }
}

// kNN v7: one block (256 threads) per query row; candidates = 256*CPT rows.
// Distance phase in float with 4 independent min accumulators; flip to
// sortable u32 only for the per-thread min and survivors. (-2) distributed
// into the query point (bit-exact: pow2 scaling commutes with RN).
//  1) per-thread float min -> flipped u32 hmin[256]
//  2) estimator: wave 0 ranks its 64 minima; T = max{h : strict-rank < EST}
//  3) extract keys <= T;  M >= SEL => exact;  else provable fallback.
//  4) exact u64 rank-count over survivors; ranks 1..SEL-1 -> output.
template <int CPT, int SEL, int EST = 20>
__global__ __launch_bounds__(256, 8) void knn_select(
    const float4* __restrict__ vq, int vStride, int nRows,
    int* __restrict__ outIdx)
{
#pragma clang fp contract(off)
    const int tid = threadIdx.x;
    const int bi  = blockIdx.x;          // b*nRows + row
    const int b   = bi / nRows;
    const int row = bi % nRows;
    const float4* vb = vq + (size_t)b * vStride;

    const float4 p = vb[row];
    const float nx = p.x * -2.0f;
    const float ny = p.y * -2.0f;
    const float nz = p.z * -2.0f;
    const float qrow = p.w;

    float fd[CPT];
    float m0 = INFINITY, m1 = INFINITY, m2 = INFINITY, m3 = INFINITY;
#pragma unroll
    for (int s = 0; s < CPT; ++s) {
        const int j = tid + (s << 8);
        const float4 c = vb[j];
        const float t0 = (nx * c.x + ny * c.y) + nz * c.z;  // == -2*inner exact
        const float dist = (t0 + c.w) + qrow;
        fd[s] = dist;
        if ((s & 3) == 0)      m0 = fminf(m0, dist);
        else if ((s & 3) == 1) m1 = fminf(m1, dist);
        else if ((s & 3) == 2) m2 = fminf(m2, dist);
        else                   m3 = fminf(m3, dist);
    }
    const float dmin = fminf(fminf(m0, m1), fminf(m2, m3));
    const unsigned umin = flipf(dmin);

    constexpr int CAP = (CPT * SEL > 256) ? CPT * SEL : 256;
    __shared__ unsigned long long buf[CAP];
    __shared__ unsigned hmin[256];
    __shared__ unsigned T_s, T2_s;
    __shared__ int cnt;

    hmin[tid] = umin;
    if (tid == 0) { T_s = 0u; T2_s = 0u; cnt = 0; }
    __syncthreads();

    // estimator threshold from wave 0's 64 minima
    if (tid < 64) {
        int r = 0;
#pragma unroll 8
        for (int i = 0; i < 64; ++i) r += (hmin[i] < umin) ? 1 : 0;
        if (r < EST) atomicMax(&T_s, umin);
    }
    __syncthreads();
    float Tf = unflip(T_s);

#pragma unroll
    for (int s = 0; s < CPT; ++s) {
        if (fd[s] <= Tf) {
            const int p2 = atomicAdd(&cnt, 1);
            if (p2 < CAP)
                buf[p2] = (((unsigned long long)flipf(fd[s])) << 32)
                        | (unsigned)(tid + (s << 8));
        }
    }
    __syncthreads();
    int M = cnt;

    if (M < SEL || M > CAP) {            // rare: provable fallback (exact)
        int r = 0;
#pragma unroll 8
        for (int i = 0; i < 256; ++i) r += (hmin[i] < umin) ? 1 : 0;
        if (r < SEL) atomicMax(&T2_s, umin);
        if (tid == 0) cnt = 0;
        __syncthreads();
        Tf = unflip(T2_s);               // >= SEL keys <= T2; M2 <= SEL*CPT
#pragma unroll
        for (int s = 0; s < CPT; ++s) {
            if (fd[s] <= Tf) {
                const int p2 = atomicAdd(&cnt, 1);
                buf[p2] = (((unsigned long long)flipf(fd[s])) << 32)
                        | (unsigned)(tid + (s << 8));
            }
        }
        __syncthreads();
        M = cnt;
    }

    for (int s2 = tid; s2 < M; s2 += 256) {
        const unsigned long long k = buf[s2];
        int rr = 0;
        for (int i = 0; i < M; ++i) rr += (buf[i] < k) ? 1 : 0;
        if (rr >= 1 && rr < SEL)
            outIdx[(size_t)bi * (SEL - 1) + (rr - 1)] = (int)(k & 0xffffffffu);
    }
}

// Unified conv: if fout==nullptr this is conv_surface (f_support=1, f_center=0).
template <int NT>
__global__ __launch_bounds__(NT) void conv_kernel(
    const int*    __restrict__ idx,   // (B, V, NN)
    const float4* __restrict__ vq,    // (B, vStride)
    int vStride, int V, int NN,
    const float* __restrict__ fout,   // (B, V, 2*oc) or nullptr
    int oc,
    const float* __restrict__ dirs,   // (3, oc)
    float* __restrict__ out,          // (B, V, oc)
    int do_relu)
{
#pragma clang fp contract(off)
    __shared__ float dnx[64], dny[64], dnz[64];
    __shared__ int   nb[64];
    const int bi  = blockIdx.x;     // b*V + i
    const int b   = bi / V;
    const int i   = bi % V;
    const int tid = threadIdx.x;

    if (tid < NN) {
        const int j = idx[(size_t)bi * NN + tid];
        nb[tid] = j;
        const float4 ci = vq[(size_t)b * vStride + i];
        const float4 cj = vq[(size_t)b * vStride + j];
        const float dx = cj.x - ci.x;
        const float dy = cj.y - ci.y;
        const float dz = cj.z - ci.z;
        const float n  = sqrtf((dx * dx + dy * dy) + dz * dz);
        const float dn = fmaxf(n, 1e-12f);
        dnx[tid] = dx / dn;
        dny[tid] = dy / dn;
        dnz[tid] = dz / dn;
    }
    __syncthreads();

    for (int c = tid; c < oc; c += NT) {
        float d0 = dirs[c], d1 = dirs[oc + c], d2 = dirs[2 * oc + c];
        const float nd = sqrtf((d0 * d0 + d1 * d1) + d2 * d2);
        const float dc = fmaxf(nd, 1e-12f);
        d0 /= dc; d1 /= dc; d2 /= dc;

        float fcen = 0.f;
        if (fout) fcen = fout[(size_t)bi * (2 * oc) + c];

        float m = -INFINITY;
        for (int n = 0; n < NN; ++n) {
            float th = (dnx[n] * d0 + dny[n] * d1) + dnz[n] * d2;
            th = fmaxf(th, 0.f);
            float fs = 1.f;
            if (fout) fs = fout[((size_t)b * V + nb[n]) * (2 * oc) + oc + c];
            m = fmaxf(m, th * fs);
        }
        float r = fcen + m;
        if (do_relu) r = fmaxf(r, 0.f);
        out[(size_t)bi * oc + c] = r;
    }
}

// out(M,N) = A(M,K) @ W(K,N) + bias(N). 64x64 tile, BK=32, 256 threads,
// 4x4 per thread.
__global__ __launch_bounds__(256) void gemm_tiled(
    const float* __restrict__ A, const float* __restrict__ W,
    const float* __restrict__ bias, float* __restrict__ out,
    int M, int K, int N)
{
    __shared__ float As[32][68];
    __shared__ float Bs[32][64];
    const int tid = threadIdx.x;
    const int tx = tid & 15, ty = tid >> 4;
    const int r0 = blockIdx.x * 64;
    const int c0 = blockIdx.y * 64;

    const float4 bv = *(const float4*)&bias[c0 + tx * 4];
    float acc[4][4];
#pragma unroll
    for (int i = 0; i < 4; ++i) {
        acc[i][0] = bv.x; acc[i][1] = bv.y; acc[i][2] = bv.z; acc[i][3] = bv.w;
    }

    const int rowA = tid >> 2;
    const int ca4  = tid & 3;
    const int rowB = tid >> 4;
    const int cb4  = tid & 15;

    for (int k0 = 0; k0 < K; k0 += 32) {
        const float4 a0 = *(const float4*)&A[(size_t)(r0 + rowA) * K + k0 + ca4 * 4];
        const float4 a1 = *(const float4*)&A[(size_t)(r0 + rowA) * K + k0 + (ca4 + 4) * 4];
        const float4 b0 = *(const float4*)&W[(size_t)(k0 + rowB) * N + c0 + cb4 * 4];
        const float4 b1 = *(const float4*)&W[(size_t)(k0 + rowB + 16) * N + c0 + cb4 * 4];
        __syncthreads();
        As[ca4 * 4 + 0][rowA] = a0.x;
        As[ca4 * 4 + 1][rowA] = a0.y;
        As[ca4 * 4 + 2][rowA] = a0.z;
        As[ca4 * 4 + 3][rowA] = a0.w;
        As[ca4 * 4 + 16][rowA] = a1.x;
        As[ca4 * 4 + 17][rowA] = a1.y;
        As[ca4 * 4 + 18][rowA] = a1.z;
        As[ca4 * 4 + 19][rowA] = a1.w;
        *(float4*)&Bs[rowB][cb4 * 4]      = b0;
        *(float4*)&Bs[rowB + 16][cb4 * 4] = b1;
        __syncthreads();
#pragma unroll
        for (int kk = 0; kk < 32; ++kk) {
            const float4 av = *(const float4*)&As[kk][ty * 4];
            const float4 wv = *(const float4*)&Bs[kk][tx * 4];
            acc[0][0] += av.x * wv.x; acc[0][1] += av.x * wv.y;
            acc[0][2] += av.x * wv.z; acc[0][3] += av.x * wv.w;
            acc[1][0] += av.y * wv.x; acc[1][1] += av.y * wv.y;
            acc[1][2] += av.y * wv.z; acc[1][3] += av.y * wv.w;
            acc[2][0] += av.z * wv.x; acc[2][1] += av.z * wv.y;
            acc[2][2] += av.z * wv.z; acc[2][3] += av.z * wv.w;
            acc[3][0] += av.w * wv.x; acc[3][1] += av.w * wv.y;
            acc[3][2] += av.w * wv.z; acc[3][3] += av.w * wv.w;
        }
    }
#pragma unroll
    for (int i = 0; i < 4; ++i) {
        float4 o;
        o.x = acc[i][0]; o.y = acc[i][1]; o.z = acc[i][2]; o.w = acc[i][3];
        *(float4*)&out[(size_t)(r0 + ty * 4 + i) * N + c0 + tx * 4] = o;
    }
}

// flat grid: one thread per (b, i, c). pooled = max over first-4 of 50-NN row.
__global__ __launch_bounds__(256) void pool_max(
    const int* __restrict__ idxNN, int nnStride, const float* __restrict__ fm,
    int Vin, int pn, int C, float* __restrict__ out)
{
    const int t  = blockIdx.x * 256 + threadIdx.x;
    const int c  = t % C;
    const int bi = t / C;            // b*pn + i
    const int b  = bi / pn;
    const int i  = bi % pn;
    const int* r = idxNN + (size_t)(b * Vin + i) * nnStride;
    const int j0 = r[0], j1 = r[1], j2 = r[2], j3 = r[3];
    float m = fm[((size_t)b * Vin + j0) * C + c];
    m = fmaxf(m, fm[((size_t)b * Vin + j1) * C + c]);
    m = fmaxf(m, fm[((size_t)b * Vin + j2) * C + c]);
    m = fmaxf(m, fm[((size_t)b * Vin + j3) * C + c]);
    out[(size_t)bi * C + c] = m;
}

// partial column max over a chunk of rows. grid (C/256, B, nChunk).
__global__ __launch_bounds__(256) void colmax_part(
    const float* __restrict__ fm, int V, int C, int rowsPerChunk,
    float* __restrict__ part)
{
    const int b = blockIdx.y, chunk = blockIdx.z;
    const int nChunk = gridDim.z;
    const int c = blockIdx.x * 256 + threadIdx.x;
    const int i0 = chunk * rowsPerChunk;
    float m = -INFINITY;
    for (int i = i0; i < i0 + rowsPerChunk; ++i)
        m = fmaxf(m, fm[((size_t)b * V + i) * C + c]);
    part[((size_t)b * nChunk + chunk) * C + c] = m;
}

// out[b, :256] = (max-merge of partials)[b, :1024] @ W(1024,256) + bias
__global__ __launch_bounds__(256) void fc_kernel(
    const float* __restrict__ part, const float* __restrict__ W,
    const float* __restrict__ bias, float* __restrict__ out, int nChunk)
{
    __shared__ float f[1024];
    const int b = blockIdx.x, tid = threadIdx.x;
    for (int k = tid; k < 1024; k += 256) {
        float m = part[((size_t)b * nChunk) * 1024 + k];
        for (int ch = 1; ch < nChunk; ++ch)
            m = fmaxf(m, part[((size_t)b * nChunk + ch) * 1024 + k]);
        f[k] = m;
    }
    __syncthreads();
    float acc = bias[tid];
    for (int k = 0; k < 1024; ++k) acc += f[k] * W[(size_t)k * 256 + tid];
    out[(size_t)b * 256 + tid] = acc;
}

extern "C" void kernel_launch(void* const* d_in, const int* in_sizes, int n_in,
                              void* d_out, int out_size, void* d_ws, size_t ws_size,
                              hipStream_t stream) {
    const float* verts = (const float*)d_in[0];
    const float* dir0  = (const float*)d_in[1];
    const float* w1 = (const float*)d_in[2];
    const float* b1 = (const float*)d_in[3];
    const float* d1 = (const float*)d_in[4];
    const float* w2 = (const float*)d_in[5];
    const float* b2 = (const float*)d_in[6];
    const float* d2 = (const float*)d_in[7];
    const float* w3 = (const float*)d_in[8];
    const float* b3 = (const float*)d_in[9];
    const float* d3 = (const float*)d_in[10];
    const float* w4 = (const float*)d_in[11];
    const float* b4 = (const float*)d_in[12];
    const float* d4 = (const float*)d_in[13];
    const float* fcw = (const float*)d_in[14];
    const float* fcb = (const float*)d_in[15];

    const int B = 2, V1 = 8192, V2 = 2048, V3 = 512, NN = 50;

    char* ws = (char*)d_ws;
    float*  arena1 = (float*)(ws + 0);          //  8,388,608 : fout1 / fout3 / fout4
    float*  arena2 = (float*)(ws + 8388608);    //  4,194,304 : fm1 / fm3 / fm4
    float*  arena3 = (float*)(ws + 12582912);   //  4,194,304 : fout2
    int*    arena4 = (int*)  (ws + 16777216);   //  3,276,800 : idxA / idxB / idxC
    float*  arena5 = (float*)(ws + 20054016);   //  2,097,152 : fm0 / fm2
    float*  arena6 = (float*)(ws + 22151168);   //  1,048,576 : fm1p / fm3p
    float*  part   = (float*)(ws + 23265280);   //     65,536 : colmax partials
    float4* vq     = (float4*)(ws + 23330816);  //    262,144 : packed {x,y,z,q}

    precompute_vq<<<(B * V1 + 255) / 256, 256, 0, stream>>>(verts, vq, B * V1);

    // ---- Stage 1 (V=8192) ----
    int* idxA = arena4;
    knn_select<32, 51><<<B * V1, 256, 0, stream>>>(vq, V1, V1, idxA);

    float* fm0 = arena5;
    conv_kernel<64><<<B * V1, 64, 0, stream>>>(idxA, vq, V1, V1, NN,
                                               nullptr, 32, dir0, fm0, 1);
    float* fout1 = arena1;
    gemm_tiled<<<dim3(B * V1 / 64, 128 / 64), 256, 0, stream>>>(
        fm0, w1, b1, fout1, B * V1, 32, 128);
    float* fm1 = arena2;
    conv_kernel<64><<<B * V1, 64, 0, stream>>>(idxA, vq, V1, V1, NN,
                                               fout1, 64, d1, fm1, 1);
    // pool 8192 -> 2048 : 4-NN = first 4 of the 50-NN rows
    float* fm1p = arena6;
    pool_max<<<B * V2 * 64 / 256, 256, 0, stream>>>(idxA, NN, fm1, V1, V2, 64, fm1p);

    // ---- Stage 2 (V=2048) ----
    int* idxB = arena4;
    knn_select<8, 51><<<B * V2, 256, 0, stream>>>(vq, V1, V2, idxB);
    float* fout2 = arena3;
    gemm_tiled<<<dim3(B * V2 / 64, 256 / 64), 256, 0, stream>>>(
        fm1p, w2, b2, fout2, B * V2, 64, 256);
    float* fm2 = arena5;
    conv_kernel<128><<<B * V2, 128, 0, stream>>>(idxB, vq, V1, V2, NN,
                                                 fout2, 128, d2, fm2, 1);
    float* fout3 = arena1;
    gemm_tiled<<<dim3(B * V2 / 64, 512 / 64), 256, 0, stream>>>(
        fm2, w3, b3, fout3, B * V2, 128, 512);
    float* fm3 = arena2;
    conv_kernel<256><<<B * V2, 256, 0, stream>>>(idxB, vq, V1, V2, NN,
                                                 fout3, 256, d3, fm3, 1);
    // pool 2048 -> 512 : 4-NN = first 4 of the 50-NN rows
    float* fm3p = arena6;
    pool_max<<<B * V3 * 256 / 256, 256, 0, stream>>>(idxB, NN, fm3, V2, V3, 256, fm3p);

    // ---- Stage 3 (V=512) ----
    int* idxC = arena4;
    knn_select<2, 51><<<B * V3, 256, 0, stream>>>(vq, V1, V3, idxC);
    float* fout4 = arena1;
    gemm_tiled<<<dim3(B * V3 / 64, 2048 / 64), 256, 0, stream>>>(
        fm3p, w4, b4, fout4, B * V3, 256, 2048);
    float* fm4 = arena2;
    conv_kernel<256><<<B * V3, 256, 0, stream>>>(idxC, vq, V1, V3, NN,
                                                 fout4, 1024, d4, fm4, 0);
    // ---- Head ----
    colmax_part<<<dim3(1024 / 256, B, 8), 256, 0, stream>>>(fm4, V3, 1024, V3 / 8, part);
    fc_kernel<<<B, 256, 0, stream>>>(part, fcw, fcb, (float*)d_out, 8);
}

// Round 8
// 400.233 us; speedup vs baseline: 1.0683x; 1.0683x over previous
//
#include <hip/hip_runtime.h>
#include <cmath>

// ---------------------------------------------------------------------------
// PointCloudFeatureExtractor — full pipeline port (fp32).
// Round 8: 8-queries-per-block kNN, no per-thread distance array (recompute
//          in extraction pass) -> no spills, 8x less L2 traffic.
// ---------------------------------------------------------------------------

__device__ __forceinline__ unsigned flipf(float f) {
    unsigned u = __float_as_uint(f);
    return (u & 0x80000000u) ? ~u : (u | 0x80000000u);
}
__device__ __forceinline__ float unflip(unsigned u) {
    unsigned r = (u & 0x80000000u) ? (u & 0x7fffffffu) : ~u;
    return __uint_as_float(r);
}

// vq[i] = {x, y, z, (x*x+y*y)+z*z}  (exact op order of the distance formula)
__global__ __launch_bounds__(256) void precompute_vq(
    const float* __restrict__ v, float4* __restrict__ vq, int n)
{
#pragma clang fp contract(off)
    const int i = blockIdx.x * 256 + threadIdx.x;
    if (i < n) {
        const float x = v[i * 3 + 0];
        const float y = v[i * 3 + 1];
        const float z = v[i * 3 + 2];
        float4 o; o.x = x; o.y = y; o.z = z; o.w = (x * x + y * y) + z * z;
        vq[i] = o;
    }
}

// kNN v8: one block (256 threads) handles QPB=8 query rows; candidates =
// 256*CPT rows shared across the 8 queries (one load -> 8 distance evals).
//  pass1: per-thread per-query float min -> flipped u32 hmin[q][256]
//  est:   group g (32 thr) ranks the 64 wave-0 minima of query g;
//         T_g = max{h : strict-rank < EST}.  E[survivors] ~ 4*EST.
//  pass2: recompute distances, extract keys <= T_g per query (cap CAPQ).
//         M >= SEL  =>  true top-SEL all among survivors  =>  exact.
//  fallback (rare, serialized per query): provable threshold over all 256
//         minima (>= SEL keys <= T2, survivors <= SEL*CPT by construction).
//  rank:  exact u64 rank-count; ranks 1..SEL-1 -> output (rank 0 = self).
// Distance math bit-identical to the validated round-1 kernel; (-2) is
// distributed into the query point (pow2 scaling commutes with RN).
template <int CPT, int SEL, int QPB = 8, int EST = 20, int CAPQ = 160>
__global__ __launch_bounds__(256) void knn_select(
    const float4* __restrict__ vq, int vStride, int nRows,
    int* __restrict__ outIdx)
{
#pragma clang fp contract(off)
    const int tid  = threadIdx.x;
    const int bpb  = nRows / QPB;           // query-blocks per batch
    const int b    = blockIdx.x / bpb;
    const int row0 = (blockIdx.x % bpb) * QPB;
    const float4* vb = vq + (size_t)b * vStride;

    float nx[QPB], ny[QPB], nz[QPB], qw[QPB];
#pragma unroll
    for (int qq = 0; qq < QPB; ++qq) {
        const float4 p = vb[row0 + qq];
        nx[qq] = p.x * -2.0f; ny[qq] = p.y * -2.0f; nz[qq] = p.z * -2.0f;
        qw[qq] = p.w;
    }

    // ---- pass 1: per-thread min per query ----
    float mn[QPB];
#pragma unroll
    for (int qq = 0; qq < QPB; ++qq) mn[qq] = INFINITY;
#pragma unroll 2
    for (int s = 0; s < CPT; ++s) {
        const float4 c = vb[tid + (s << 8)];
#pragma unroll
        for (int qq = 0; qq < QPB; ++qq) {
            const float t0 = (nx[qq] * c.x + ny[qq] * c.y) + nz[qq] * c.z;
            const float dist = (t0 + c.w) + qw[qq];
            mn[qq] = fminf(mn[qq], dist);
        }
    }

    __shared__ unsigned hmin[QPB][256];
    __shared__ unsigned long long bufq[QPB][CAPQ];
    __shared__ unsigned long long fbuf[CPT * SEL];
    __shared__ unsigned Ts[QPB];
    __shared__ int cnt[QPB];
    __shared__ unsigned T2_s;
    __shared__ int fcnt;

#pragma unroll
    for (int qq = 0; qq < QPB; ++qq) hmin[qq][tid] = flipf(mn[qq]);
    if (tid < QPB) { Ts[tid] = 0u; cnt[tid] = 0; }
    __syncthreads();

    // ---- estimator: 32-thread group g ranks wave-0's 64 minima of query g
    {
        const int g = tid >> 5, i = tid & 31;
#pragma unroll
        for (int hh = 0; hh < 2; ++hh) {
            const unsigned vv = hmin[g][i + hh * 32];
            int r = 0;
#pragma unroll 8
            for (int k = 0; k < 64; ++k) r += (hmin[g][k] < vv) ? 1 : 0;
            if (r < EST) atomicMax(&Ts[g], vv);
        }
    }
    __syncthreads();

    float Tf[QPB];
#pragma unroll
    for (int qq = 0; qq < QPB; ++qq) Tf[qq] = unflip(Ts[qq]);

    // ---- pass 2: extraction (recompute distances) ----
#pragma unroll 2
    for (int s = 0; s < CPT; ++s) {
        const int j = tid + (s << 8);
        const float4 c = vb[j];
#pragma unroll
        for (int qq = 0; qq < QPB; ++qq) {
            const float t0 = (nx[qq] * c.x + ny[qq] * c.y) + nz[qq] * c.z;
            const float dist = (t0 + c.w) + qw[qq];
            if (dist <= Tf[qq]) {
                const int p = atomicAdd(&cnt[qq], 1);
                if (p < CAPQ)
                    bufq[qq][p] = (((unsigned long long)flipf(dist)) << 32)
                                | (unsigned)j;
            }
        }
    }
    __syncthreads();

    // ---- per-query exactness check; rare provable fallback (serialized) ----
    for (int qq = 0; qq < QPB; ++qq) {
        const int M = cnt[qq];
        if (M >= SEL && M <= CAPQ) continue;     // uniform branch
        if (tid == 0) { T2_s = 0u; fcnt = 0; }
        __syncthreads();
        {
            const unsigned vv = hmin[qq][tid];
            int r = 0;
            for (int k = 0; k < 256; ++k) r += (hmin[qq][k] < vv) ? 1 : 0;
            if (r < SEL) atomicMax(&T2_s, vv);
        }
        __syncthreads();
        const float T2f = unflip(T2_s);
#pragma unroll 2
        for (int s = 0; s < CPT; ++s) {
            const int j = tid + (s << 8);
            const float4 c = vb[j];
            const float t0 = (nx[qq] * c.x + ny[qq] * c.y) + nz[qq] * c.z;
            const float dist = (t0 + c.w) + qw[qq];
            if (dist <= T2f) {
                const int p = atomicAdd(&fcnt, 1);
                fbuf[p] = (((unsigned long long)flipf(dist)) << 32) | (unsigned)j;
            }
        }
        __syncthreads();
        const int M2 = fcnt;
        for (int s2 = tid; s2 < M2; s2 += 256) {
            const unsigned long long k = fbuf[s2];
            int rr = 0;
            for (int i2 = 0; i2 < M2; ++i2) rr += (fbuf[i2] < k) ? 1 : 0;
            if (rr >= 1 && rr < SEL)
                outIdx[(size_t)(b * nRows + row0 + qq) * (SEL - 1) + (rr - 1)]
                    = (int)(k & 0xffffffffu);
        }
        if (tid == 0) cnt[qq] = 0;               // mark handled
        __syncthreads();
    }

    // ---- final ranking: 32-thread group per query ----
    {
        const int g = tid >> 5, i = tid & 31;
        const int M = cnt[g];                    // 0 if handled by fallback
        for (int s2 = i; s2 < M; s2 += 32) {
            const unsigned long long k = bufq[g][s2];
            int rr = 0;
            for (int i2 = 0; i2 < M; ++i2) rr += (bufq[g][i2] < k) ? 1 : 0;
            if (rr >= 1 && rr < SEL)
                outIdx[(size_t)(b * nRows + row0 + g) * (SEL - 1) + (rr - 1)]
                    = (int)(k & 0xffffffffu);
        }
    }
}

// Unified conv: if fout==nullptr this is conv_surface (f_support=1, f_center=0).
template <int NT>
__global__ __launch_bounds__(NT) void conv_kernel(
    const int*    __restrict__ idx,   // (B, V, NN)
    const float4* __restrict__ vq,    // (B, vStride)
    int vStride, int V, int NN,
    const float* __restrict__ fout,   // (B, V, 2*oc) or nullptr
    int oc,
    const float* __restrict__ dirs,   // (3, oc)
    float* __restrict__ out,          // (B, V, oc)
    int do_relu)
{
#pragma clang fp contract(off)
    __shared__ float dnx[64], dny[64], dnz[64];
    __shared__ int   nb[64];
    const int bi  = blockIdx.x;     // b*V + i
    const int b   = bi / V;
    const int i   = bi % V;
    const int tid = threadIdx.x;

    if (tid < NN) {
        const int j = idx[(size_t)bi * NN + tid];
        nb[tid] = j;
        const float4 ci = vq[(size_t)b * vStride + i];
        const float4 cj = vq[(size_t)b * vStride + j];
        const float dx = cj.x - ci.x;
        const float dy = cj.y - ci.y;
        const float dz = cj.z - ci.z;
        const float n  = sqrtf((dx * dx + dy * dy) + dz * dz);
        const float dn = fmaxf(n, 1e-12f);
        dnx[tid] = dx / dn;
        dny[tid] = dy / dn;
        dnz[tid] = dz / dn;
    }
    __syncthreads();

    for (int c = tid; c < oc; c += NT) {
        float d0 = dirs[c], d1 = dirs[oc + c], d2 = dirs[2 * oc + c];
        const float nd = sqrtf((d0 * d0 + d1 * d1) + d2 * d2);
        const float dc = fmaxf(nd, 1e-12f);
        d0 /= dc; d1 /= dc; d2 /= dc;

        float fcen = 0.f;
        if (fout) fcen = fout[(size_t)bi * (2 * oc) + c];

        float m = -INFINITY;
        for (int n = 0; n < NN; ++n) {
            float th = (dnx[n] * d0 + dny[n] * d1) + dnz[n] * d2;
            th = fmaxf(th, 0.f);
            float fs = 1.f;
            if (fout) fs = fout[((size_t)b * V + nb[n]) * (2 * oc) + oc + c];
            m = fmaxf(m, th * fs);
        }
        float r = fcen + m;
        if (do_relu) r = fmaxf(r, 0.f);
        out[(size_t)bi * oc + c] = r;
    }
}

// out(M,N) = A(M,K) @ W(K,N) + bias(N). 64x64 tile, BK=32, 256 threads,
// 4x4 per thread.
__global__ __launch_bounds__(256) void gemm_tiled(
    const float* __restrict__ A, const float* __restrict__ W,
    const float* __restrict__ bias, float* __restrict__ out,
    int M, int K, int N)
{
    __shared__ float As[32][68];
    __shared__ float Bs[32][64];
    const int tid = threadIdx.x;
    const int tx = tid & 15, ty = tid >> 4;
    const int r0 = blockIdx.x * 64;
    const int c0 = blockIdx.y * 64;

    const float4 bv = *(const float4*)&bias[c0 + tx * 4];
    float acc[4][4];
#pragma unroll
    for (int i = 0; i < 4; ++i) {
        acc[i][0] = bv.x; acc[i][1] = bv.y; acc[i][2] = bv.z; acc[i][3] = bv.w;
    }

    const int rowA = tid >> 2;
    const int ca4  = tid & 3;
    const int rowB = tid >> 4;
    const int cb4  = tid & 15;

    for (int k0 = 0; k0 < K; k0 += 32) {
        const float4 a0 = *(const float4*)&A[(size_t)(r0 + rowA) * K + k0 + ca4 * 4];
        const float4 a1 = *(const float4*)&A[(size_t)(r0 + rowA) * K + k0 + (ca4 + 4) * 4];
        const float4 b0 = *(const float4*)&W[(size_t)(k0 + rowB) * N + c0 + cb4 * 4];
        const float4 b1 = *(const float4*)&W[(size_t)(k0 + rowB + 16) * N + c0 + cb4 * 4];
        __syncthreads();
        As[ca4 * 4 + 0][rowA] = a0.x;
        As[ca4 * 4 + 1][rowA] = a0.y;
        As[ca4 * 4 + 2][rowA] = a0.z;
        As[ca4 * 4 + 3][rowA] = a0.w;
        As[ca4 * 4 + 16][rowA] = a1.x;
        As[ca4 * 4 + 17][rowA] = a1.y;
        As[ca4 * 4 + 18][rowA] = a1.z;
        As[ca4 * 4 + 19][rowA] = a1.w;
        *(float4*)&Bs[rowB][cb4 * 4]      = b0;
        *(float4*)&Bs[rowB + 16][cb4 * 4] = b1;
        __syncthreads();
#pragma unroll
        for (int kk = 0; kk < 32; ++kk) {
            const float4 av = *(const float4*)&As[kk][ty * 4];
            const float4 wv = *(const float4*)&Bs[kk][tx * 4];
            acc[0][0] += av.x * wv.x; acc[0][1] += av.x * wv.y;
            acc[0][2] += av.x * wv.z; acc[0][3] += av.x * wv.w;
            acc[1][0] += av.y * wv.x; acc[1][1] += av.y * wv.y;
            acc[1][2] += av.y * wv.z; acc[1][3] += av.y * wv.w;
            acc[2][0] += av.z * wv.x; acc[2][1] += av.z * wv.y;
            acc[2][2] += av.z * wv.z; acc[2][3] += av.z * wv.w;
            acc[3][0] += av.w * wv.x; acc[3][1] += av.w * wv.y;
            acc[3][2] += av.w * wv.z; acc[3][3] += av.w * wv.w;
        }
    }
#pragma unroll
    for (int i = 0; i < 4; ++i) {
        float4 o;
        o.x = acc[i][0]; o.y = acc[i][1]; o.z = acc[i][2]; o.w = acc[i][3];
        *(float4*)&out[(size_t)(r0 + ty * 4 + i) * N + c0 + tx * 4] = o;
    }
}

// flat grid: one thread per (b, i, c). pooled = max over first-4 of 50-NN row.
__global__ __launch_bounds__(256) void pool_max(
    const int* __restrict__ idxNN, int nnStride, const float* __restrict__ fm,
    int Vin, int pn, int C, float* __restrict__ out)
{
    const int t  = blockIdx.x * 256 + threadIdx.x;
    const int c  = t % C;
    const int bi = t / C;            // b*pn + i
    const int b  = bi / pn;
    const int i  = bi % pn;
    const int* r = idxNN + (size_t)(b * Vin + i) * nnStride;
    const int j0 = r[0], j1 = r[1], j2 = r[2], j3 = r[3];
    float m = fm[((size_t)b * Vin + j0) * C + c];
    m = fmaxf(m, fm[((size_t)b * Vin + j1) * C + c]);
    m = fmaxf(m, fm[((size_t)b * Vin + j2) * C + c]);
    m = fmaxf(m, fm[((size_t)b * Vin + j3) * C + c]);
    out[(size_t)bi * C + c] = m;
}

// partial column max over a chunk of rows. grid (C/256, B, nChunk).
__global__ __launch_bounds__(256) void colmax_part(
    const float* __restrict__ fm, int V, int C, int rowsPerChunk,
    float* __restrict__ part)
{
    const int b = blockIdx.y, chunk = blockIdx.z;
    const int nChunk = gridDim.z;
    const int c = blockIdx.x * 256 + threadIdx.x;
    const int i0 = chunk * rowsPerChunk;
    float m = -INFINITY;
    for (int i = i0; i < i0 + rowsPerChunk; ++i)
        m = fmaxf(m, fm[((size_t)b * V + i) * C + c]);
    part[((size_t)b * nChunk + chunk) * C + c] = m;
}

// out[b, :256] = (max-merge of partials)[b, :1024] @ W(1024,256) + bias
__global__ __launch_bounds__(256) void fc_kernel(
    const float* __restrict__ part, const float* __restrict__ W,
    const float* __restrict__ bias, float* __restrict__ out, int nChunk)
{
    __shared__ float f[1024];
    const int b = blockIdx.x, tid = threadIdx.x;
    for (int k = tid; k < 1024; k += 256) {
        float m = part[((size_t)b * nChunk) * 1024 + k];
        for (int ch = 1; ch < nChunk; ++ch)
            m = fmaxf(m, part[((size_t)b * nChunk + ch) * 1024 + k]);
        f[k] = m;
    }
    __syncthreads();
    float acc = bias[tid];
    for (int k = 0; k < 1024; ++k) acc += f[k] * W[(size_t)k * 256 + tid];
    out[(size_t)b * 256 + tid] = acc;
}

extern "C" void kernel_launch(void* const* d_in, const int* in_sizes, int n_in,
                              void* d_out, int out_size, void* d_ws, size_t ws_size,
                              hipStream_t stream) {
    const float* verts = (const float*)d_in[0];
    const float* dir0  = (const float*)d_in[1];
    const float* w1 = (const float*)d_in[2];
    const float* b1 = (const float*)d_in[3];
    const float* d1 = (const float*)d_in[4];
    const float* w2 = (const float*)d_in[5];
    const float* b2 = (const float*)d_in[6];
    const float* d2 = (const float*)d_in[7];
    const float* w3 = (const float*)d_in[8];
    const float* b3 = (const float*)d_in[9];
    const float* d3 = (const float*)d_in[10];
    const float* w4 = (const float*)d_in[11];
    const float* b4 = (const float*)d_in[12];
    const float* d4 = (const float*)d_in[13];
    const float* fcw = (const float*)d_in[14];
    const float* fcb = (const float*)d_in[15];

    const int B = 2, V1 = 8192, V2 = 2048, V3 = 512, NN = 50;

    char* ws = (char*)d_ws;
    float*  arena1 = (float*)(ws + 0);          //  8,388,608 : fout1 / fout3 / fout4
    float*  arena2 = (float*)(ws + 8388608);    //  4,194,304 : fm1 / fm3 / fm4
    float*  arena3 = (float*)(ws + 12582912);   //  4,194,304 : fout2
    int*    arena4 = (int*)  (ws + 16777216);   //  3,276,800 : idxA / idxB / idxC
    float*  arena5 = (float*)(ws + 20054016);   //  2,097,152 : fm0 / fm2
    float*  arena6 = (float*)(ws + 22151168);   //  1,048,576 : fm1p / fm3p
    float*  part   = (float*)(ws + 23265280);   //     65,536 : colmax partials
    float4* vq     = (float4*)(ws + 23330816);  //    262,144 : packed {x,y,z,q}

    precompute_vq<<<(B * V1 + 255) / 256, 256, 0, stream>>>(verts, vq, B * V1);

    // ---- Stage 1 (V=8192) ----
    int* idxA = arena4;
    knn_select<32, 51><<<B * V1 / 8, 256, 0, stream>>>(vq, V1, V1, idxA);

    float* fm0 = arena5;
    conv_kernel<64><<<B * V1, 64, 0, stream>>>(idxA, vq, V1, V1, NN,
                                               nullptr, 32, dir0, fm0, 1);
    float* fout1 = arena1;
    gemm_tiled<<<dim3(B * V1 / 64, 128 / 64), 256, 0, stream>>>(
        fm0, w1, b1, fout1, B * V1, 32, 128);
    float* fm1 = arena2;
    conv_kernel<64><<<B * V1, 64, 0, stream>>>(idxA, vq, V1, V1, NN,
                                               fout1, 64, d1, fm1, 1);
    // pool 8192 -> 2048 : 4-NN = first 4 of the 50-NN rows
    float* fm1p = arena6;
    pool_max<<<B * V2 * 64 / 256, 256, 0, stream>>>(idxA, NN, fm1, V1, V2, 64, fm1p);

    // ---- Stage 2 (V=2048) ----
    int* idxB = arena4;
    knn_select<8, 51><<<B * V2 / 8, 256, 0, stream>>>(vq, V1, V2, idxB);
    float* fout2 = arena3;
    gemm_tiled<<<dim3(B * V2 / 64, 256 / 64), 256, 0, stream>>>(
        fm1p, w2, b2, fout2, B * V2, 64, 256);
    float* fm2 = arena5;
    conv_kernel<128><<<B * V2, 128, 0, stream>>>(idxB, vq, V1, V2, NN,
                                                 fout2, 128, d2, fm2, 1);
    float* fout3 = arena1;
    gemm_tiled<<<dim3(B * V2 / 64, 512 / 64), 256, 0, stream>>>(
        fm2, w3, b3, fout3, B * V2, 128, 512);
    float* fm3 = arena2;
    conv_kernel<256><<<B * V2, 256, 0, stream>>>(idxB, vq, V1, V2, NN,
                                                 fout3, 256, d3, fm3, 1);
    // pool 2048 -> 512 : 4-NN = first 4 of the 50-NN rows
    float* fm3p = arena6;
    pool_max<<<B * V3 * 256 / 256, 256, 0, stream>>>(idxB, NN, fm3, V2, V3, 256, fm3p);

    // ---- Stage 3 (V=512) ----
    int* idxC = arena4;
    knn_select<2, 51><<<B * V3 / 8, 256, 0, stream>>>(vq, V1, V3, idxC);
    float* fout4 = arena1;
    gemm_tiled<<<dim3(B * V3 / 64, 2048 / 64), 256, 0, stream>>>(
        fm3p, w4, b4, fout4, B * V3, 256, 2048);
    float* fm4 = arena2;
    conv_kernel<256><<<B * V3, 256, 0, stream>>>(idxC, vq, V1, V3, NN,
                                                 fout4, 1024, d4, fm4, 0);
    // ---- Head ----
    colmax_part<<<dim3(1024 / 256, B, 8), 256, 0, stream>>>(fm4, V3, 1024, V3 / 8, part);
    fc_kernel<<<B, 256, 0, stream>>>(part, fcw, fcb, (float*)d_out, 8);
}

// Round 9
// 364.738 us; speedup vs baseline: 1.1723x; 1.0973x over previous
//
#include <hip/hip_runtime.h>
#include <cmath>

// ---------------------------------------------------------------------------
// PointCloudFeatureExtractor — full pipeline port (fp32).
// Round 9: conv gather-batching (10 independent loads in flight, fmax order
//          unchanged) + channel-split grid for the oc=1024 conv.
// ---------------------------------------------------------------------------

__device__ __forceinline__ unsigned flipf(float f) {
    unsigned u = __float_as_uint(f);
    return (u & 0x80000000u) ? ~u : (u | 0x80000000u);
}
__device__ __forceinline__ float unflip(unsigned u) {
    unsigned r = (u & 0x80000000u) ? (u & 0x7fffffffu) : ~u;
    return __uint_as_float(r);
}

// vq[i] = {x, y, z, (x*x+y*y)+z*z}  (exact op order of the distance formula)
__global__ __launch_bounds__(256) void precompute_vq(
    const float* __restrict__ v, float4* __restrict__ vq, int n)
{
#pragma clang fp contract(off)
    const int i = blockIdx.x * 256 + threadIdx.x;
    if (i < n) {
        const float x = v[i * 3 + 0];
        const float y = v[i * 3 + 1];
        const float z = v[i * 3 + 2];
        float4 o; o.x = x; o.y = y; o.z = z; o.w = (x * x + y * y) + z * z;
        vq[i] = o;
    }
}

// kNN v8 (unchanged from round 8): QPB queries per block, 2-pass
// estimator/extract with provable fallback. Exact, bit-identical ordering.
template <int CPT, int SEL, int QPB = 8, int EST = 20, int CAPQ = 160>
__global__ __launch_bounds__(256) void knn_select(
    const float4* __restrict__ vq, int vStride, int nRows,
    int* __restrict__ outIdx)
{
#pragma clang fp contract(off)
    const int tid  = threadIdx.x;
    const int bpb  = nRows / QPB;
    const int b    = blockIdx.x / bpb;
    const int row0 = (blockIdx.x % bpb) * QPB;
    const float4* vb = vq + (size_t)b * vStride;

    float nx[QPB], ny[QPB], nz[QPB], qw[QPB];
#pragma unroll
    for (int qq = 0; qq < QPB; ++qq) {
        const float4 p = vb[row0 + qq];
        nx[qq] = p.x * -2.0f; ny[qq] = p.y * -2.0f; nz[qq] = p.z * -2.0f;
        qw[qq] = p.w;
    }

    float mn[QPB];
#pragma unroll
    for (int qq = 0; qq < QPB; ++qq) mn[qq] = INFINITY;
#pragma unroll 2
    for (int s = 0; s < CPT; ++s) {
        const float4 c = vb[tid + (s << 8)];
#pragma unroll
        for (int qq = 0; qq < QPB; ++qq) {
            const float t0 = (nx[qq] * c.x + ny[qq] * c.y) + nz[qq] * c.z;
            const float dist = (t0 + c.w) + qw[qq];
            mn[qq] = fminf(mn[qq], dist);
        }
    }

    __shared__ unsigned hmin[QPB][256];
    __shared__ unsigned long long bufq[QPB][CAPQ];
    __shared__ unsigned long long fbuf[CPT * SEL];
    __shared__ unsigned Ts[QPB];
    __shared__ int cnt[QPB];
    __shared__ unsigned T2_s;
    __shared__ int fcnt;

#pragma unroll
    for (int qq = 0; qq < QPB; ++qq) hmin[qq][tid] = flipf(mn[qq]);
    if (tid < QPB) { Ts[tid] = 0u; cnt[tid] = 0; }
    __syncthreads();

    {
        const int g = tid >> 5, i = tid & 31;
#pragma unroll
        for (int hh = 0; hh < 2; ++hh) {
            const unsigned vv = hmin[g][i + hh * 32];
            int r = 0;
#pragma unroll 8
            for (int k = 0; k < 64; ++k) r += (hmin[g][k] < vv) ? 1 : 0;
            if (r < EST) atomicMax(&Ts[g], vv);
        }
    }
    __syncthreads();

    float Tf[QPB];
#pragma unroll
    for (int qq = 0; qq < QPB; ++qq) Tf[qq] = unflip(Ts[qq]);

#pragma unroll 2
    for (int s = 0; s < CPT; ++s) {
        const int j = tid + (s << 8);
        const float4 c = vb[j];
#pragma unroll
        for (int qq = 0; qq < QPB; ++qq) {
            const float t0 = (nx[qq] * c.x + ny[qq] * c.y) + nz[qq] * c.z;
            const float dist = (t0 + c.w) + qw[qq];
            if (dist <= Tf[qq]) {
                const int p = atomicAdd(&cnt[qq], 1);
                if (p < CAPQ)
                    bufq[qq][p] = (((unsigned long long)flipf(dist)) << 32)
                                | (unsigned)j;
            }
        }
    }
    __syncthreads();

    for (int qq = 0; qq < QPB; ++qq) {
        const int M = cnt[qq];
        if (M >= SEL && M <= CAPQ) continue;
        if (tid == 0) { T2_s = 0u; fcnt = 0; }
        __syncthreads();
        {
            const unsigned vv = hmin[qq][tid];
            int r = 0;
            for (int k = 0; k < 256; ++k) r += (hmin[qq][k] < vv) ? 1 : 0;
            if (r < SEL) atomicMax(&T2_s, vv);
        }
        __syncthreads();
        const float T2f = unflip(T2_s);
#pragma unroll 2
        for (int s = 0; s < CPT; ++s) {
            const int j = tid + (s << 8);
            const float4 c = vb[j];
            const float t0 = (nx[qq] * c.x + ny[qq] * c.y) + nz[qq] * c.z;
            const float dist = (t0 + c.w) + qw[qq];
            if (dist <= T2f) {
                const int p = atomicAdd(&fcnt, 1);
                fbuf[p] = (((unsigned long long)flipf(dist)) << 32) | (unsigned)j;
            }
        }
        __syncthreads();
        const int M2 = fcnt;
        for (int s2 = tid; s2 < M2; s2 += 256) {
            const unsigned long long k = fbuf[s2];
            int rr = 0;
            for (int i2 = 0; i2 < M2; ++i2) rr += (fbuf[i2] < k) ? 1 : 0;
            if (rr >= 1 && rr < SEL)
                outIdx[(size_t)(b * nRows + row0 + qq) * (SEL - 1) + (rr - 1)]
                    = (int)(k & 0xffffffffu);
        }
        if (tid == 0) cnt[qq] = 0;
        __syncthreads();
    }

    {
        const int g = tid >> 5, i = tid & 31;
        const int M = cnt[g];
        for (int s2 = i; s2 < M; s2 += 32) {
            const unsigned long long k = bufq[g][s2];
            int rr = 0;
            for (int i2 = 0; i2 < M; ++i2) rr += (bufq[g][i2] < k) ? 1 : 0;
            if (rr >= 1 && rr < SEL)
                outIdx[(size_t)(b * nRows + row0 + g) * (SEL - 1) + (rr - 1)]
                    = (int)(k & 0xffffffffu);
        }
    }
}

// Unified conv v2: gather loads batched (BN=10 independent loads in flight);
// fmax accumulation order identical to v1 (bit-exact). Channel range can be
// split across gridDim.y blocks (for large oc).
template <int NT>
__global__ __launch_bounds__(NT) void conv_kernel(
    const int*    __restrict__ idx,   // (B, V, NN)
    const float4* __restrict__ vq,    // (B, vStride)
    int vStride, int V, int NN,
    const float* __restrict__ fout,   // (B, V, 2*oc) or nullptr
    int oc,
    const float* __restrict__ dirs,   // (3, oc)
    float* __restrict__ out,          // (B, V, oc)
    int do_relu)
{
#pragma clang fp contract(off)
    __shared__ float dnx[64], dny[64], dnz[64];
    __shared__ int   nb[64];
    const int bi  = blockIdx.x;     // b*V + i
    const int b   = bi / V;
    const int i   = bi % V;
    const int tid = threadIdx.x;

    if (tid < NN) {
        const int j = idx[(size_t)bi * NN + tid];
        nb[tid] = j;
        const float4 ci = vq[(size_t)b * vStride + i];
        const float4 cj = vq[(size_t)b * vStride + j];
        const float dx = cj.x - ci.x;
        const float dy = cj.y - ci.y;
        const float dz = cj.z - ci.z;
        const float n  = sqrtf((dx * dx + dy * dy) + dz * dz);
        const float dn = fmaxf(n, 1e-12f);
        dnx[tid] = dx / dn;
        dny[tid] = dy / dn;
        dnz[tid] = dz / dn;
    }
    __syncthreads();

    const int ocPer = oc / gridDim.y;
    const int cLo   = blockIdx.y * ocPer;
    const float* fsup = fout ? (fout + (size_t)b * V * (2 * oc) + oc) : nullptr;

    for (int c = cLo + tid; c < cLo + ocPer; c += NT) {
        float d0 = dirs[c], d1 = dirs[oc + c], d2 = dirs[2 * oc + c];
        const float nd = sqrtf((d0 * d0 + d1 * d1) + d2 * d2);
        const float dc = fmaxf(nd, 1e-12f);
        d0 /= dc; d1 /= dc; d2 /= dc;

        float fcen = 0.f;
        if (fout) fcen = fout[(size_t)bi * (2 * oc) + c];

        float m = -INFINITY;
        constexpr int BN = 10;
        for (int n0 = 0; n0 < 50; n0 += BN) {
            float fs[BN];
            if (fout) {
#pragma unroll
                for (int u = 0; u < BN; ++u)
                    fs[u] = fsup[(size_t)nb[n0 + u] * (2 * oc) + c];
            } else {
#pragma unroll
                for (int u = 0; u < BN; ++u) fs[u] = 1.f;
            }
#pragma unroll
            for (int u = 0; u < BN; ++u) {
                const int n = n0 + u;
                float th = (dnx[n] * d0 + dny[n] * d1) + dnz[n] * d2;
                th = fmaxf(th, 0.f);
                m = fmaxf(m, th * fs[u]);
            }
        }
        float r = fcen + m;
        if (do_relu) r = fmaxf(r, 0.f);
        out[(size_t)bi * oc + c] = r;
    }
}

// out(M,N) = A(M,K) @ W(K,N) + bias(N). 64x64 tile, BK=32, 256 threads,
// 4x4 per thread.
__global__ __launch_bounds__(256) void gemm_tiled(
    const float* __restrict__ A, const float* __restrict__ W,
    const float* __restrict__ bias, float* __restrict__ out,
    int M, int K, int N)
{
    __shared__ float As[32][68];
    __shared__ float Bs[32][64];
    const int tid = threadIdx.x;
    const int tx = tid & 15, ty = tid >> 4;
    const int r0 = blockIdx.x * 64;
    const int c0 = blockIdx.y * 64;

    const float4 bv = *(const float4*)&bias[c0 + tx * 4];
    float acc[4][4];
#pragma unroll
    for (int i = 0; i < 4; ++i) {
        acc[i][0] = bv.x; acc[i][1] = bv.y; acc[i][2] = bv.z; acc[i][3] = bv.w;
    }

    const int rowA = tid >> 2;
    const int ca4  = tid & 3;
    const int rowB = tid >> 4;
    const int cb4  = tid & 15;

    for (int k0 = 0; k0 < K; k0 += 32) {
        const float4 a0 = *(const float4*)&A[(size_t)(r0 + rowA) * K + k0 + ca4 * 4];
        const float4 a1 = *(const float4*)&A[(size_t)(r0 + rowA) * K + k0 + (ca4 + 4) * 4];
        const float4 b0 = *(const float4*)&W[(size_t)(k0 + rowB) * N + c0 + cb4 * 4];
        const float4 b1 = *(const float4*)&W[(size_t)(k0 + rowB + 16) * N + c0 + cb4 * 4];
        __syncthreads();
        As[ca4 * 4 + 0][rowA] = a0.x;
        As[ca4 * 4 + 1][rowA] = a0.y;
        As[ca4 * 4 + 2][rowA] = a0.z;
        As[ca4 * 4 + 3][rowA] = a0.w;
        As[ca4 * 4 + 16][rowA] = a1.x;
        As[ca4 * 4 + 17][rowA] = a1.y;
        As[ca4 * 4 + 18][rowA] = a1.z;
        As[ca4 * 4 + 19][rowA] = a1.w;
        *(float4*)&Bs[rowB][cb4 * 4]      = b0;
        *(float4*)&Bs[rowB + 16][cb4 * 4] = b1;
        __syncthreads();
#pragma unroll
        for (int kk = 0; kk < 32; ++kk) {
            const float4 av = *(const float4*)&As[kk][ty * 4];
            const float4 wv = *(const float4*)&Bs[kk][tx * 4];
            acc[0][0] += av.x * wv.x; acc[0][1] += av.x * wv.y;
            acc[0][2] += av.x * wv.z; acc[0][3] += av.x * wv.w;
            acc[1][0] += av.y * wv.x; acc[1][1] += av.y * wv.y;
            acc[1][2] += av.y * wv.z; acc[1][3] += av.y * wv.w;
            acc[2][0] += av.z * wv.x; acc[2][1] += av.z * wv.y;
            acc[2][2] += av.z * wv.z; acc[2][3] += av.z * wv.w;
            acc[3][0] += av.w * wv.x; acc[3][1] += av.w * wv.y;
            acc[3][2] += av.w * wv.z; acc[3][3] += av.w * wv.w;
        }
    }
#pragma unroll
    for (int i = 0; i < 4; ++i) {
        float4 o;
        o.x = acc[i][0]; o.y = acc[i][1]; o.z = acc[i][2]; o.w = acc[i][3];
        *(float4*)&out[(size_t)(r0 + ty * 4 + i) * N + c0 + tx * 4] = o;
    }
}

// flat grid: one thread per (b, i, c). pooled = max over first-4 of 50-NN row.
__global__ __launch_bounds__(256) void pool_max(
    const int* __restrict__ idxNN, int nnStride, const float* __restrict__ fm,
    int Vin, int pn, int C, float* __restrict__ out)
{
    const int t  = blockIdx.x * 256 + threadIdx.x;
    const int c  = t % C;
    const int bi = t / C;            // b*pn + i
    const int b  = bi / pn;
    const int i  = bi % pn;
    const int* r = idxNN + (size_t)(b * Vin + i) * nnStride;
    const int j0 = r[0], j1 = r[1], j2 = r[2], j3 = r[3];
    float m = fm[((size_t)b * Vin + j0) * C + c];
    m = fmaxf(m, fm[((size_t)b * Vin + j1) * C + c]);
    m = fmaxf(m, fm[((size_t)b * Vin + j2) * C + c]);
    m = fmaxf(m, fm[((size_t)b * Vin + j3) * C + c]);
    out[(size_t)bi * C + c] = m;
}

// partial column max over a chunk of rows. grid (C/256, B, nChunk).
__global__ __launch_bounds__(256) void colmax_part(
    const float* __restrict__ fm, int V, int C, int rowsPerChunk,
    float* __restrict__ part)
{
    const int b = blockIdx.y, chunk = blockIdx.z;
    const int nChunk = gridDim.z;
    const int c = blockIdx.x * 256 + threadIdx.x;
    const int i0 = chunk * rowsPerChunk;
    float m = -INFINITY;
    for (int i = i0; i < i0 + rowsPerChunk; ++i)
        m = fmaxf(m, fm[((size_t)b * V + i) * C + c]);
    part[((size_t)b * nChunk + chunk) * C + c] = m;
}

// out[b, :256] = (max-merge of partials)[b, :1024] @ W(1024,256) + bias
__global__ __launch_bounds__(256) void fc_kernel(
    const float* __restrict__ part, const float* __restrict__ W,
    const float* __restrict__ bias, float* __restrict__ out, int nChunk)
{
    __shared__ float f[1024];
    const int b = blockIdx.x, tid = threadIdx.x;
    for (int k = tid; k < 1024; k += 256) {
        float m = part[((size_t)b * nChunk) * 1024 + k];
        for (int ch = 1; ch < nChunk; ++ch)
            m = fmaxf(m, part[((size_t)b * nChunk + ch) * 1024 + k]);
        f[k] = m;
    }
    __syncthreads();
    float acc = bias[tid];
    for (int k = 0; k < 1024; ++k) acc += f[k] * W[(size_t)k * 256 + tid];
    out[(size_t)b * 256 + tid] = acc;
}

extern "C" void kernel_launch(void* const* d_in, const int* in_sizes, int n_in,
                              void* d_out, int out_size, void* d_ws, size_t ws_size,
                              hipStream_t stream) {
    const float* verts = (const float*)d_in[0];
    const float* dir0  = (const float*)d_in[1];
    const float* w1 = (const float*)d_in[2];
    const float* b1 = (const float*)d_in[3];
    const float* d1 = (const float*)d_in[4];
    const float* w2 = (const float*)d_in[5];
    const float* b2 = (const float*)d_in[6];
    const float* d2 = (const float*)d_in[7];
    const float* w3 = (const float*)d_in[8];
    const float* b3 = (const float*)d_in[9];
    const float* d3 = (const float*)d_in[10];
    const float* w4 = (const float*)d_in[11];
    const float* b4 = (const float*)d_in[12];
    const float* d4 = (const float*)d_in[13];
    const float* fcw = (const float*)d_in[14];
    const float* fcb = (const float*)d_in[15];

    const int B = 2, V1 = 8192, V2 = 2048, V3 = 512, NN = 50;

    char* ws = (char*)d_ws;
    float*  arena1 = (float*)(ws + 0);          //  8,388,608 : fout1 / fout3 / fout4
    float*  arena2 = (float*)(ws + 8388608);    //  4,194,304 : fm1 / fm3 / fm4
    float*  arena3 = (float*)(ws + 12582912);   //  4,194,304 : fout2
    int*    arena4 = (int*)  (ws + 16777216);   //  3,276,800 : idxA / idxB / idxC
    float*  arena5 = (float*)(ws + 20054016);   //  2,097,152 : fm0 / fm2
    float*  arena6 = (float*)(ws + 22151168);   //  1,048,576 : fm1p / fm3p
    float*  part   = (float*)(ws + 23265280);   //     65,536 : colmax partials
    float4* vq     = (float4*)(ws + 23330816);  //    262,144 : packed {x,y,z,q}

    precompute_vq<<<(B * V1 + 255) / 256, 256, 0, stream>>>(verts, vq, B * V1);

    // ---- Stage 1 (V=8192) ----
    int* idxA = arena4;
    knn_select<32, 51><<<B * V1 / 8, 256, 0, stream>>>(vq, V1, V1, idxA);

    float* fm0 = arena5;
    conv_kernel<64><<<dim3(B * V1, 1), 64, 0, stream>>>(idxA, vq, V1, V1, NN,
                                                        nullptr, 32, dir0, fm0, 1);
    float* fout1 = arena1;
    gemm_tiled<<<dim3(B * V1 / 64, 128 / 64), 256, 0, stream>>>(
        fm0, w1, b1, fout1, B * V1, 32, 128);
    float* fm1 = arena2;
    conv_kernel<64><<<dim3(B * V1, 1), 64, 0, stream>>>(idxA, vq, V1, V1, NN,
                                                        fout1, 64, d1, fm1, 1);
    // pool 8192 -> 2048 : 4-NN = first 4 of the 50-NN rows
    float* fm1p = arena6;
    pool_max<<<B * V2 * 64 / 256, 256, 0, stream>>>(idxA, NN, fm1, V1, V2, 64, fm1p);

    // ---- Stage 2 (V=2048) ----
    int* idxB = arena4;
    knn_select<8, 51><<<B * V2 / 8, 256, 0, stream>>>(vq, V1, V2, idxB);
    float* fout2 = arena3;
    gemm_tiled<<<dim3(B * V2 / 64, 256 / 64), 256, 0, stream>>>(
        fm1p, w2, b2, fout2, B * V2, 64, 256);
    float* fm2 = arena5;
    conv_kernel<128><<<dim3(B * V2, 1), 128, 0, stream>>>(idxB, vq, V1, V2, NN,
                                                          fout2, 128, d2, fm2, 1);
    float* fout3 = arena1;
    gemm_tiled<<<dim3(B * V2 / 64, 512 / 64), 256, 0, stream>>>(
        fm2, w3, b3, fout3, B * V2, 128, 512);
    float* fm3 = arena2;
    conv_kernel<256><<<dim3(B * V2, 1), 256, 0, stream>>>(idxB, vq, V1, V2, NN,
                                                          fout3, 256, d3, fm3, 1);
    // pool 2048 -> 512 : 4-NN = first 4 of the 50-NN rows
    float* fm3p = arena6;
    pool_max<<<B * V3 * 256 / 256, 256, 0, stream>>>(idxB, NN, fm3, V2, V3, 256, fm3p);

    // ---- Stage 3 (V=512) ----
    int* idxC = arena4;
    knn_select<2, 51><<<B * V3 / 8, 256, 0, stream>>>(vq, V1, V3, idxC);
    float* fout4 = arena1;
    gemm_tiled<<<dim3(B * V3 / 64, 2048 / 64), 256, 0, stream>>>(
        fm3p, w4, b4, fout4, B * V3, 256, 2048);
    float* fm4 = arena2;
    // oc=1024 split across 4 channel-blocks: 1 channel/thread, 4x the waves
    conv_kernel<256><<<dim3(B * V3, 4), 256, 0, stream>>>(idxC, vq, V1, V3, NN,
                                                          fout4, 1024, d4, fm4, 0);
    // ---- Head ----
    colmax_part<<<dim3(1024 / 256, B, 8), 256, 0, stream>>>(fm4, V3, 1024, V3 / 8, part);
    fc_kernel<<<B, 256, 0, stream>>>(part, fcw, fcb, (float*)d_out, 8);
}